// Round 7
// baseline (43.953 us; speedup 1.0000x reference)
//
#include <hip/hip_runtime.h>

// KnnLinearFixModel: B=512, K=64, D=1024, L=8, 20 SGD steps.
// W_t = c^t*W0 + S_t^T X (c=1-LR*WD) -> phase 1 computes G=X*X^T, M0=X*W0^T,
// q=X*e, p0=W0*e in one pass (MFMA Gram trick, R5). Phase 3 closed form (R6):
// logits = c^20 p0 + w^T z_20 via binomial expansion in H (2 G-matvecs).
// R7: phase 1 depth-2 register pipeline. Two 19-float4 chunk buffers; chunk
// i+2's loads issue during chunk i's store+MFMA step -> each wave keeps 19-38
// loads in flight CONTINUOUSLY (depth-1 had ~40% dead time with zero requests,
// capping aggregate BW at ~4.9 TB/s). VGPR ~240 is intended: we are pinned at
// 2 waves/SIMD anyway (launch_bounds 256,2); LDS staging region unchanged
// (single, wave-private; in-order DS pipe makes read-before-overwrite safe).

#define BB 512
#define KK 64
#define DD 1024
#define LL 8

#define SROWS 80             // 64 X rows + 16 P rows (0-7 W0, 8 e, 9-15 zero)
#define SSTR  72             // shorts/row: 144 B, 16B-aligned rows for b128
#define NTILE 15             // 10 G (upper tri) + 4 M + 1 PP
#define ARENA_BYTES (4 * NTILE * 256 * 4)   // 61440; staging needs 4*11520

typedef __attribute__((ext_vector_type(8))) short bf16x8;
typedef __attribute__((ext_vector_type(4))) float f32x4;

// ---- compile-time coefficient algebra (double, exact enough) ----
constexpr double dLRS = 1e-4 * 2.0 / (64.0 * 8.0);   // LR*scale = 3.90625e-7
constexpr double dC   = 1.0 - 1e-4 * 0.01;           // c = 1 - LR*WD
constexpr double dpow(double x, int n) { double r = 1; for (int i = 0; i < n; ++i) r *= x; return r; }
// P1 = sum_{t=0..19} c^t F^{19-t} = sum_m C(20,m+1) c^{19-m} (-LRS H)^m
// P2 = sum_{j=0..19} F^j        = sum_m D_m (-LRS H)^m, D_m = sum_j C(j,m)c^{j-m}
// F^20 = sum_m C(20,m) c^{20-m} (-LRS H)^m
constexpr double dD0() { double s = 0; for (int j = 0; j < 20; ++j) s += dpow(dC, j); return s; }
constexpr double dD1() { double s = 0; for (int j = 1; j < 20; ++j) s += j * dpow(dC, j - 1); return s; }
constexpr double dD2() { double s = 0; for (int j = 2; j < 20; ++j) s += (j * (j - 1) / 2) * dpow(dC, j - 2); return s; }

__device__ __forceinline__ short f2bf(float f) {
    // round-to-nearest-even f32 -> bf16 (finite inputs only)
    unsigned u = __float_as_uint(f);
    unsigned r = (u + 0x7FFFu + ((u >> 16) & 1u)) >> 16;
    return (short)r;
}

#define MFMA16(A, B, C) __builtin_amdgcn_mfma_f32_16x16x32_bf16(A, B, C, 0, 0, 0)

__global__ __launch_bounds__(256, 2)
void knn_linear_fix_kernel(const float* __restrict__ demo,   // [B,K,D]
                           const float* __restrict__ emb,    // [B,D]
                           const float* __restrict__ W0,     // [B,L,D]
                           const float* __restrict__ b0,     // [B,L]
                           const int*   __restrict__ labels, // [B,K]
                           float* __restrict__ out)          // [B,L]
{
    const int b    = blockIdx.x;
    const int t    = threadIdx.x;
    const int lane = t & 63;
    const int wid  = t >> 6;          // wave id 0..3 == D-slice id
    const int lg   = lane >> 4;       // lane group 0..3
    const int lr   = lane & 15;       // row (A) / col (B, C/D) index

    __shared__ __align__(16) char arena[ARENA_BYTES]; // staging / exchange
    __shared__ short Gs[64 * 72];    // G bf16, stride 72
    __shared__ short Ss[16 * 72];    // broadcast t-vector as B-frag [col][k]
    __shared__ float Ms[64 * 16];    // cols 0-7 = M0 = X W0^T, col 8 = q = X.e
    __shared__ float red[256];
    __shared__ float p0_s[16];       // p0 = W0 . e
    __shared__ int   lab_s[64];

    const float* Xg = demo + (size_t)b * (KK * DD);
    const float* Wg = W0   + (size_t)b * (LL * DD);
    const float* eg = emb  + (size_t)b * DD;

    short* Xw = (short*)arena + wid * (SROWS * SSTR);  // wave-private staging
    float* Ex = (float*)arena;                         // exchange view

    const int g  = lane >> 4;        // load row-group 0..3
    const int cl = (lane & 15) * 4;  // load col (floats): 16 lanes x 16B = 256B

    float4 xa[16]; float4 pa[3];     // chunk buffer A
    float4 xb[16]; float4 pb[3];     // chunk buffer B

#define LOADCH(XB, PB, CH) do {                                                  \
        const int doff = wid * 256 + (CH) * 64;                                  \
        _Pragma("unroll")                                                        \
        for (int r = 0; r < 16; ++r)                                             \
            (XB)[r] = *(const float4*)(Xg + (size_t)(r * 4 + g) * DD + doff + cl); \
        (PB)[0] = *(const float4*)(Wg + (size_t)(g    ) * DD + doff + cl);       \
        (PB)[1] = *(const float4*)(Wg + (size_t)(g + 4) * DD + doff + cl);       \
        (PB)[2] = (g == 0) ? *(const float4*)(eg + doff + cl)                    \
                           : make_float4(0.f, 0.f, 0.f, 0.f);                    \
    } while (0)

#define ST1(ROW, V) do {                                                         \
        short4 h;                                                                \
        h.x = f2bf((V).x); h.y = f2bf((V).y);                                    \
        h.z = f2bf((V).z); h.w = f2bf((V).w);                                    \
        *(short4*)(&Xw[(ROW) * SSTR + cl]) = h;                                  \
    } while (0)

#define STORECH(XB, PB) do {                                                     \
        _Pragma("unroll")                                                        \
        for (int r = 0; r < 16; ++r) ST1(r * 4 + g, (XB)[r]);                    \
        ST1(64 + g, (PB)[0]);                                                    \
        ST1(68 + g, (PB)[1]);                                                    \
        if (g == 0) ST1(72, (PB)[2]);                                            \
    } while (0)

#define FRAG(I, KS) (*(const bf16x8*)(&Xw[(16 * (I) + lr) * SSTR + lg * 8 + (KS) * 32]))
#define FRAGP(KS)   (*(const bf16x8*)(&Xw[(64 + lr) * SSTR + lg * 8 + (KS) * 32]))

#define MFMA_CHUNK() do {                                                        \
        __builtin_amdgcn_sched_barrier(0);                                       \
        _Pragma("unroll")                                                        \
        for (int ks = 0; ks < 2; ++ks) {                                         \
            const bf16x8 f0 = FRAG(0, ks), f1 = FRAG(1, ks);                     \
            const bf16x8 f2 = FRAG(2, ks), f3 = FRAG(3, ks);                     \
            const bf16x8 fp = FRAGP(ks);                                         \
            g00 = MFMA16(f0, f0, g00); g01 = MFMA16(f0, f1, g01);                \
            g02 = MFMA16(f0, f2, g02); g03 = MFMA16(f0, f3, g03);                \
            g11 = MFMA16(f1, f1, g11); g12 = MFMA16(f1, f2, g12);                \
            g13 = MFMA16(f1, f3, g13);                                           \
            g22 = MFMA16(f2, f2, g22); g23 = MFMA16(f2, f3, g23);                \
            g33 = MFMA16(f3, f3, g33);                                           \
            am0 = MFMA16(f0, fp, am0); am1 = MFMA16(f1, fp, am1);                \
            am2 = MFMA16(f2, fp, am2); am3 = MFMA16(f3, fp, am3);                \
            app = MFMA16(fp, fp, app);                                           \
        }                                                                        \
        __builtin_amdgcn_sched_barrier(0);                                       \
    } while (0)

    f32x4 g00 = {0,0,0,0}, g01 = {0,0,0,0}, g02 = {0,0,0,0}, g03 = {0,0,0,0};
    f32x4 g11 = {0,0,0,0}, g12 = {0,0,0,0}, g13 = {0,0,0,0};
    f32x4 g22 = {0,0,0,0}, g23 = {0,0,0,0}, g33 = {0,0,0,0};
    f32x4 am0 = {0,0,0,0}, am1 = {0,0,0,0}, am2 = {0,0,0,0}, am3 = {0,0,0,0};
    f32x4 app = {0,0,0,0};

    // ---------------- Phase 1: 4 chunks/wave, depth-2 register pipeline
    LOADCH(xa, pa, 0);               // chunk 0 in flight
    LOADCH(xb, pb, 1);               // chunk 1 in flight

    // init work fills the first load's latency
    if (t < 64) lab_s[t] = labels[b * KK + t];
    float bc = (lr < 8) ? b0[b * LL + lr] : 0.0f;      // bias, replicated
    {   // zero wave-private staging pad rows 73..79 (P rows 9-15), once
        int* zp = (int*)(Xw + 73 * SSTR);
        for (int i = lane; i < (7 * SSTR) / 2; i += 64) zp[i] = 0;
    }

    // chunk 0
    STORECH(xa, pa);                 // waits chunk-0 loads
    LOADCH(xa, pa, 2);               // chunk 2 in flight (consumed 2 steps later)
    MFMA_CHUNK();
    // chunk 1
    STORECH(xb, pb);
    LOADCH(xb, pb, 3);               // chunk 3 in flight
    MFMA_CHUNK();
    // chunk 2
    STORECH(xa, pa);
    MFMA_CHUNK();
    // chunk 3
    STORECH(xb, pb);
    MFMA_CHUNK();

    // ---------------- Phase 2: cross-wave f32 reduce of 15 tiles, scatter
    __syncthreads();                    // staging regions -> exchange arena
    {
        float* Exw = Ex + wid * (NTILE * 256);
        const int ro = (lg * 4) * 16 + lr;   // C/D: row=lg*4+r, col=lr
#define PUT(IDX, ACC) { _Pragma("unroll") \
        for (int r = 0; r < 4; ++r) Exw[(IDX) * 256 + ro + r * 16] = (ACC)[r]; }
        PUT(0, g00) PUT(1, g01) PUT(2, g02) PUT(3, g03)
        PUT(4, g11) PUT(5, g12) PUT(6, g13)
        PUT(7, g22) PUT(8, g23) PUT(9, g33)
        PUT(10, am0) PUT(11, am1) PUT(12, am2) PUT(13, am3)
        PUT(14, app)
#undef PUT
    }
    __syncthreads();
    {
        const int er = t >> 4, ec = t & 15;      // entry (row, col) in a tile
        const int ti[10] = {0,0,0,0,1,1,1,2,2,3};
        const int tj[10] = {0,1,2,3,1,2,3,2,3,3};
        #pragma unroll
        for (int k = 0; k < 10; ++k) {
            float v = Ex[0 * NTILE * 256 + k * 256 + t]
                    + Ex[1 * NTILE * 256 + k * 256 + t]
                    + Ex[2 * NTILE * 256 + k * 256 + t]
                    + Ex[3 * NTILE * 256 + k * 256 + t];
            const short gv = f2bf(v);
            const int gr = ti[k] * 16 + er, gc = tj[k] * 16 + ec;
            Gs[gr * 72 + gc] = gv;
            Gs[gc * 72 + gr] = gv;      // symmetry (bitwise-equal on diagonal)
        }
        #pragma unroll
        for (int k = 0; k < 4; ++k) {
            float v = Ex[0 * NTILE * 256 + (10 + k) * 256 + t]
                    + Ex[1 * NTILE * 256 + (10 + k) * 256 + t]
                    + Ex[2 * NTILE * 256 + (10 + k) * 256 + t]
                    + Ex[3 * NTILE * 256 + (10 + k) * 256 + t];
            Ms[(k * 16 + er) * 16 + ec] = v;
        }
        {
            float v = Ex[0 * NTILE * 256 + 14 * 256 + t]
                    + Ex[1 * NTILE * 256 + 14 * 256 + t]
                    + Ex[2 * NTILE * 256 + 14 * 256 + t]
                    + Ex[3 * NTILE * 256 + 14 * 256 + t];
            if (er == 8) p0_s[ec] = v;  // row 8 of P P^T = e . P[col]
        }
    }
    __syncthreads();

    // ---------------- Phase 3 (closed form): w1 = H^T w, w2 = H^T w1, assemble
    const float pM0 = (float)(-dLRS * 20.0  * dpow(dC, 19));
    const float pM1 = (float)( dLRS * dLRS * 190.0  * dpow(dC, 18));
    const float pM2 = (float)(-dLRS * dLRS * dLRS * 1140.0 * dpow(dC, 17));
    const float pY0 = (float)( dLRS * dD0());
    const float pY1 = (float)(-dLRS * dLRS * dD1());
    const float pY2 = (float)( dLRS * dLRS * dLRS * dD2());
    const float kG0 = (float)dpow(dC, 20);

    const int row0 = wid * 16 + lg * 4;

    // fill A: Ss[col][k] = bf16(q[k] + 1) for all 16 cols (column-broadcast)
    {
        const int ct = t & 15, k0 = (t >> 4) * 4;
        short4 sp;
        sp.x = f2bf(Ms[(k0 + 0) * 16 + 8] + 1.0f);
        sp.y = f2bf(Ms[(k0 + 1) * 16 + 8] + 1.0f);
        sp.z = f2bf(Ms[(k0 + 2) * 16 + 8] + 1.0f);
        sp.w = f2bf(Ms[(k0 + 3) * 16 + 8] + 1.0f);
        *(short4*)(&Ss[ct * 72 + k0]) = sp;
    }
    // q at this thread's rows + full sum of q (butterfly; per-wave redundant)
    const float q0 = Ms[(row0 + 0) * 16 + 8];
    const float q1 = Ms[(row0 + 1) * 16 + 8];
    const float q2 = Ms[(row0 + 2) * 16 + 8];
    const float q3 = Ms[(row0 + 3) * 16 + 8];
    float qsum = Ms[lane * 16 + 8];
    #pragma unroll
    for (int m = 1; m < 64; m <<= 1) qsum += __shfl_xor(qsum, m, 64);
    const float w1b = qsum + 64.0f;          // 1^T q + 64

    const bf16x8 ga0 = *(const bf16x8*)(&Gs[(wid * 16 + lr) * 72 +  0 + lg * 8]);
    const bf16x8 ga1 = *(const bf16x8*)(&Gs[(wid * 16 + lr) * 72 + 32 + lg * 8]);

    __syncthreads();                         // fill-A visible
    // MFMA A: w1_X = G (q + 1); rows row0..row0+3 at this lane (repl over lr)
    float w10, w11, w12, w13;
    {
        const bf16x8 sb0 = *(const bf16x8*)(&Ss[lr * 72 +  0 + lg * 8]);
        const bf16x8 sb1 = *(const bf16x8*)(&Ss[lr * 72 + 32 + lg * 8]);
        f32x4 o = {0.f, 0.f, 0.f, 0.f};
        o = MFMA16(ga0, sb0, o);
        o = MFMA16(ga1, sb1, o);
        w10 = o[0]; w11 = o[1]; w12 = o[2]; w13 = o[3];
    }
    // wave partial row-sum of w1 (count each row once: lr==0 only)
    float val = (lr == 0) ? (w10 + w11 + w12 + w13) : 0.0f;
    #pragma unroll
    for (int m = 1; m < 64; m <<= 1) val += __shfl_xor(val, m, 64);
    if (lane == 0) red[wid] = val;
    __syncthreads();                         // Ss reads done; red visible

    // fill B: t1 = w1 + w1b at own rows, col = lr (covers all 16 cols)
    {
        short4 sp;
        sp.x = f2bf(w10 + w1b); sp.y = f2bf(w11 + w1b);
        sp.z = f2bf(w12 + w1b); sp.w = f2bf(w13 + w1b);
        *(short4*)(&Ss[lr * 72 + row0]) = sp;
    }
    const float w1sum = red[0] + red[1] + red[2] + red[3];
    const float w2b = w1sum + 64.0f * w1b;   // 1^T w1_X + 64 w1b
    __syncthreads();                         // fill-B visible

    // MFMA B: w2_X = G (w1_X + w1b)
    float w20, w21, w22, w23;
    {
        const bf16x8 sb0 = *(const bf16x8*)(&Ss[lr * 72 +  0 + lg * 8]);
        const bf16x8 sb1 = *(const bf16x8*)(&Ss[lr * 72 + 32 + lg * 8]);
        f32x4 o = {0.f, 0.f, 0.f, 0.f};
        o = MFMA16(ga0, sb0, o);
        o = MFMA16(ga1, sb1, o);
        w20 = o[0]; w21 = o[1]; w22 = o[2]; w23 = o[3];
    }

    // assemble: a_k = uM(k)+cM multiplies M0 rows; y_k = uY(k)+cY -> label col
    const float cM  = pM0 + pM1 * w1b + pM2 * w2b;
    const float cY  = pY0 + pY1 * w1b + pY2 * w2b;
    const float sb0c = kG0 + pM0 * w1b + pM1 * w2b;   // F^20 z0 b-coefficient

    float acc[8] = {0.f, 0.f, 0.f, 0.f, 0.f, 0.f, 0.f, 0.f};
    if (lr == 0) {
        const float qs[4]  = {q0, q1, q2, q3};
        const float w1s[4] = {w10, w11, w12, w13};
        const float w2s[4] = {w20, w21, w22, w23};
        #pragma unroll
        for (int r = 0; r < 4; ++r) {
            const int row = row0 + r;
            const float a = pM0 * qs[r] + pM1 * w1s[r] + pM2 * w2s[r] + cM;
            const float y = pY0 * qs[r] + pY1 * w1s[r] + pY2 * w2s[r] + cY;
            const int lab = lab_s[row];
            const float4 mlo = *(const float4*)(&Ms[row * 16 + 0]);
            const float4 mhi = *(const float4*)(&Ms[row * 16 + 4]);
            acc[0] += a * mlo.x + ((lab == 0) ? y : 0.f);
            acc[1] += a * mlo.y + ((lab == 1) ? y : 0.f);
            acc[2] += a * mlo.z + ((lab == 2) ? y : 0.f);
            acc[3] += a * mlo.w + ((lab == 3) ? y : 0.f);
            acc[4] += a * mhi.x + ((lab == 4) ? y : 0.f);
            acc[5] += a * mhi.y + ((lab == 5) ? y : 0.f);
            acc[6] += a * mhi.z + ((lab == 6) ? y : 0.f);
            acc[7] += a * mhi.w + ((lab == 7) ? y : 0.f);
        }
    }
    #pragma unroll
    for (int j = 0; j < 8; ++j) {
        #pragma unroll
        for (int m = 1; m < 64; m <<= 1) acc[j] += __shfl_xor(acc[j], m, 64);
    }
    if (lane == 0) {
        #pragma unroll
        for (int j = 0; j < 8; ++j) red[16 + wid * 8 + j] = acc[j];
    }
    __syncthreads();
    if (t < 8) {
        const float s = red[16 + 0 * 8 + t] + red[16 + 1 * 8 + t] +
                        red[16 + 2 * 8 + t] + red[16 + 3 * 8 + t];
        // thread t: lr == t -> bc = b0[t]
        out[b * LL + t] = kG0 * p0_s[t] + sb0c * bc + s;
    }
}

extern "C" void kernel_launch(void* const* d_in, const int* in_sizes, int n_in,
                              void* d_out, int out_size, void* d_ws, size_t ws_size,
                              hipStream_t stream) {
    const float* demo   = (const float*)d_in[0]; // demo_embeddings [512,64,1024]
    const float* emb    = (const float*)d_in[1]; // embeddings     [512,1024]
    const float* W0     = (const float*)d_in[2]; // W0             [512,8,1024]
    const float* b0     = (const float*)d_in[3]; // b0             [512,8]
    const int*   labels = (const int*)d_in[4];   // demo_labels    [512,64]
    float* out = (float*)d_out;                  // logits         [512,8] f32
    (void)in_sizes; (void)n_in; (void)out_size; (void)d_ws; (void)ws_size;
    hipLaunchKernelGGL(knn_linear_fix_kernel, dim3(BB), dim3(256), 0, stream,
                       demo, emb, W0, b0, labels, out);
}

// Round 8
// 29.474 us; speedup vs baseline: 1.4912x; 1.4912x over previous
//
#include <hip/hip_runtime.h>

// KnnLinearFixModel: B=512, K=64, D=1024, L=8, 20 SGD steps.
// W_t = c^t*W0 + S_t^T X (c=1-LR*WD) -> phase 1 computes G=X*X^T, M0=X*W0^T,
// q=X*e, p0=W0*e in one pass (MFMA Gram trick, R5). Phase 3 closed form (R6):
// logits = c^20 p0 + w^T z_20 via binomial expansion in H (2 G-matvecs).
// R8: phase 1 reverted to R6 exactly (R7's depth-2 reg pipeline spilled:
// VGPR=128 + 23MB scratch writes). Tail trim: phase-2 reduce vectorized
// (float4 reads, short4 G-writes; was 120 scalar LDS ops/thread), phase-3
// reductions use lr-replication (2-step lane-group shfl instead of 6-step
// butterflies). Phase 1 is HBM-floored (~26us): R2/R4/R5 invariance across
// three different load schedules.

#define BB 512
#define KK 64
#define DD 1024
#define LL 8

#define SROWS 80             // 64 X rows + 16 P rows (0-7 W0, 8 e, 9-15 zero)
#define SSTR  72             // shorts/row: 144 B, 16B-aligned rows for b128
#define NTILE 15             // 10 G (upper tri) + 4 M + 1 PP
#define ARENA_BYTES (4 * NTILE * 256 * 4)   // 61440; staging needs 4*11520

typedef __attribute__((ext_vector_type(8))) short bf16x8;
typedef __attribute__((ext_vector_type(4))) float f32x4;

// ---- compile-time coefficient algebra (double, exact enough) ----
constexpr double dLRS = 1e-4 * 2.0 / (64.0 * 8.0);   // LR*scale = 3.90625e-7
constexpr double dC   = 1.0 - 1e-4 * 0.01;           // c = 1 - LR*WD
constexpr double dpow(double x, int n) { double r = 1; for (int i = 0; i < n; ++i) r *= x; return r; }
// P1 = sum_{t=0..19} c^t F^{19-t} = sum_m C(20,m+1) c^{19-m} (-LRS H)^m
// P2 = sum_{j=0..19} F^j        = sum_m D_m (-LRS H)^m, D_m = sum_j C(j,m)c^{j-m}
// F^20 = sum_m C(20,m) c^{20-m} (-LRS H)^m
constexpr double dD0() { double s = 0; for (int j = 0; j < 20; ++j) s += dpow(dC, j); return s; }
constexpr double dD1() { double s = 0; for (int j = 1; j < 20; ++j) s += j * dpow(dC, j - 1); return s; }
constexpr double dD2() { double s = 0; for (int j = 2; j < 20; ++j) s += (j * (j - 1) / 2) * dpow(dC, j - 2); return s; }

__device__ __forceinline__ short f2bf(float f) {
    // round-to-nearest-even f32 -> bf16 (finite inputs only)
    unsigned u = __float_as_uint(f);
    unsigned r = (u + 0x7FFFu + ((u >> 16) & 1u)) >> 16;
    return (short)r;
}

#define MFMA16(A, B, C) __builtin_amdgcn_mfma_f32_16x16x32_bf16(A, B, C, 0, 0, 0)

__global__ __launch_bounds__(256, 2)
void knn_linear_fix_kernel(const float* __restrict__ demo,   // [B,K,D]
                           const float* __restrict__ emb,    // [B,D]
                           const float* __restrict__ W0,     // [B,L,D]
                           const float* __restrict__ b0,     // [B,L]
                           const int*   __restrict__ labels, // [B,K]
                           float* __restrict__ out)          // [B,L]
{
    const int b    = blockIdx.x;
    const int t    = threadIdx.x;
    const int lane = t & 63;
    const int wid  = t >> 6;          // wave id 0..3 == D-slice id
    const int lg   = lane >> 4;       // lane group 0..3
    const int lr   = lane & 15;       // row (A) / col (B, C/D) index

    __shared__ __align__(16) char arena[ARENA_BYTES]; // staging / exchange
    __shared__ short Gs[64 * 72];    // G bf16, stride 72
    __shared__ short Ss[16 * 72];    // broadcast t-vector as B-frag [col][k]
    __shared__ float Ms[64 * 16];    // cols 0-7 = M0 = X W0^T, col 8 = q = X.e
    __shared__ float red[256];
    __shared__ float p0_s[16];       // p0 = W0 . e
    __shared__ int   lab_s[64];

    const float* Xg = demo + (size_t)b * (KK * DD);
    const float* Wg = W0   + (size_t)b * (LL * DD);
    const float* eg = emb  + (size_t)b * DD;

    short* Xw = (short*)arena + wid * (SROWS * SSTR);  // wave-private staging
    float* Ex = (float*)arena;                         // exchange view

    if (t < 64) lab_s[t] = labels[b * KK + t];
    float bc = (lr < 8) ? b0[b * LL + lr] : 0.0f;      // bias, replicated

    // zero wave-private staging pad rows 73..79 (P rows 9-15), once
    {
        int* zp = (int*)(Xw + 73 * SSTR);
        for (int i = lane; i < (7 * SSTR) / 2; i += 64) zp[i] = 0;
    }

    const int g  = lane >> 4;        // load row-group 0..3
    const int cl = (lane & 15) * 4;  // load col (floats): 16 lanes x 16B = 256B

    float4 xb[16]; float4 pb[3];

#define LOADCH(CH) do {                                                          \
        const int doff = wid * 256 + (CH) * 64;                                  \
        _Pragma("unroll")                                                        \
        for (int r = 0; r < 16; ++r)                                             \
            xb[r] = *(const float4*)(Xg + (size_t)(r * 4 + g) * DD + doff + cl); \
        pb[0] = *(const float4*)(Wg + (size_t)(g    ) * DD + doff + cl);         \
        pb[1] = *(const float4*)(Wg + (size_t)(g + 4) * DD + doff + cl);         \
        pb[2] = (g == 0) ? *(const float4*)(eg + doff + cl)                      \
                         : make_float4(0.f, 0.f, 0.f, 0.f);                      \
    } while (0)

#define ST1(ROW, V) do {                                                         \
        short4 h;                                                                \
        h.x = f2bf((V).x); h.y = f2bf((V).y);                                    \
        h.z = f2bf((V).z); h.w = f2bf((V).w);                                    \
        *(short4*)(&Xw[(ROW) * SSTR + cl]) = h;                                  \
    } while (0)

#define STORECH() do {                                                           \
        _Pragma("unroll")                                                        \
        for (int r = 0; r < 16; ++r) ST1(r * 4 + g, xb[r]);                      \
        ST1(64 + g, pb[0]);                                                      \
        ST1(68 + g, pb[1]);                                                      \
        if (g == 0) ST1(72, pb[2]);                                              \
    } while (0)

#define FRAG(I, KS) (*(const bf16x8*)(&Xw[(16 * (I) + lr) * SSTR + lg * 8 + (KS) * 32]))
#define FRAGP(KS)   (*(const bf16x8*)(&Xw[(64 + lr) * SSTR + lg * 8 + (KS) * 32]))

    f32x4 g00 = {0,0,0,0}, g01 = {0,0,0,0}, g02 = {0,0,0,0}, g03 = {0,0,0,0};
    f32x4 g11 = {0,0,0,0}, g12 = {0,0,0,0}, g13 = {0,0,0,0};
    f32x4 g22 = {0,0,0,0}, g23 = {0,0,0,0}, g33 = {0,0,0,0};
    f32x4 am0 = {0,0,0,0}, am1 = {0,0,0,0}, am2 = {0,0,0,0}, am3 = {0,0,0,0};
    f32x4 app = {0,0,0,0};

    // ---------------- Phase 1: 4 chunks of 64 cols per wave, no barriers
    LOADCH(0);
    for (int ch = 0; ch < 4; ++ch) {
        STORECH();                       // waits its loads; in-order LDS pipe
        if (ch < 3) LOADCH(ch + 1);      // next chunk in flight during MFMAs
        __builtin_amdgcn_sched_barrier(0);
        #pragma unroll
        for (int ks = 0; ks < 2; ++ks) {
            const bf16x8 f0 = FRAG(0, ks), f1 = FRAG(1, ks);
            const bf16x8 f2 = FRAG(2, ks), f3 = FRAG(3, ks);
            const bf16x8 fp = FRAGP(ks);
            g00 = MFMA16(f0, f0, g00); g01 = MFMA16(f0, f1, g01);
            g02 = MFMA16(f0, f2, g02); g03 = MFMA16(f0, f3, g03);
            g11 = MFMA16(f1, f1, g11); g12 = MFMA16(f1, f2, g12);
            g13 = MFMA16(f1, f3, g13);
            g22 = MFMA16(f2, f2, g22); g23 = MFMA16(f2, f3, g23);
            g33 = MFMA16(f3, f3, g33);
            am0 = MFMA16(f0, fp, am0); am1 = MFMA16(f1, fp, am1);
            am2 = MFMA16(f2, fp, am2); am3 = MFMA16(f3, fp, am3);
            app = MFMA16(fp, fp, app);
        }
        __builtin_amdgcn_sched_barrier(0);
    }

    // ---------------- Phase 2: cross-wave f32 reduce of 15 tiles (vectorized)
    __syncthreads();                    // staging regions -> exchange arena
    {
        float* Exw = Ex + wid * (NTILE * 256);
        const int ro = (lg * 4) * 16 + lr;   // C/D: row=lg*4+r, col=lr
#define PUT(IDX, ACC) { _Pragma("unroll") \
        for (int r = 0; r < 4; ++r) Exw[(IDX) * 256 + ro + r * 16] = (ACC)[r]; }
        PUT(0, g00) PUT(1, g01) PUT(2, g02) PUT(3, g03)
        PUT(4, g11) PUT(5, g12) PUT(6, g13)
        PUT(7, g22) PUT(8, g23) PUT(9, g33)
        PUT(10, am0) PUT(11, am1) PUT(12, am2) PUT(13, am3)
        PUT(14, app)
#undef PUT
    }
    __syncthreads();
    {
        const float4* E0 = (const float4*)(Ex + 0 * NTILE * 256);
        const float4* E1 = (const float4*)(Ex + 1 * NTILE * 256);
        const float4* E2 = (const float4*)(Ex + 2 * NTILE * 256);
        const float4* E3 = (const float4*)(Ex + 3 * NTILE * 256);
        // G tiles: 10*256 f32 = 640 float4s
        #pragma unroll
        for (int p = 0; p < 3; ++p) {
            const int fid = p * 256 + t;
            if (fid < 640) {
                float4 v = E0[fid];
                v.x += E1[fid].x; v.y += E1[fid].y; v.z += E1[fid].z; v.w += E1[fid].w;
                v.x += E2[fid].x; v.y += E2[fid].y; v.z += E2[fid].z; v.w += E2[fid].w;
                v.x += E3[fid].x; v.y += E3[fid].y; v.z += E3[fid].z; v.w += E3[fid].w;
                const int idx = fid * 4;
                const int s   = idx >> 8;          // tile 0..9 (upper triangle)
                const int rem = idx & 255;
                const int er  = rem >> 4, ec = rem & 15;   // ec in {0,4,8,12}
                const int ti  = (s >= 4) + (s >= 7) + (s >= 9);
                const int st  = (ti == 0) ? 0 : (ti == 1) ? 4 : (ti == 2) ? 7 : 9;
                const int tj  = ti + (s - st);
                const int gr  = ti * 16 + er, gc = tj * 16 + ec;
                short4 gv;
                gv.x = f2bf(v.x); gv.y = f2bf(v.y);
                gv.z = f2bf(v.z); gv.w = f2bf(v.w);
                *(short4*)(&Gs[gr * 72 + gc]) = gv;        // primary (upper)
                Gs[(gc + 0) * 72 + gr] = gv.x;             // mirror (lower)
                Gs[(gc + 1) * 72 + gr] = gv.y;
                Gs[(gc + 2) * 72 + gr] = gv.z;
                Gs[(gc + 3) * 72 + gr] = gv.w;
            }
        }
        // M tiles + PP: 5*256 f32 = 320 float4s (offset 640)
        #pragma unroll
        for (int p = 0; p < 2; ++p) {
            const int fid = p * 256 + t;
            if (fid < 320) {
                const int f = 640 + fid;
                float4 v = E0[f];
                v.x += E1[f].x; v.y += E1[f].y; v.z += E1[f].z; v.w += E1[f].w;
                v.x += E2[f].x; v.y += E2[f].y; v.z += E2[f].z; v.w += E2[f].w;
                v.x += E3[f].x; v.y += E3[f].y; v.z += E3[f].z; v.w += E3[f].w;
                const int idx = fid * 4;
                const int mt  = idx >> 8;          // 0..3 = M tiles, 4 = PP
                const int rem = idx & 255;
                const int er  = rem >> 4, ec = rem & 15;
                if (mt < 4) {
                    *(float4*)(&Ms[(mt * 16 + er) * 16 + ec]) = v;
                } else if (er == 8) {              // row 8 of P P^T = e.P[col]
                    p0_s[ec + 0] = v.x; p0_s[ec + 1] = v.y;
                    p0_s[ec + 2] = v.z; p0_s[ec + 3] = v.w;
                }
            }
        }
    }
    __syncthreads();

    // ---------------- Phase 3 (closed form): w1 = H^T w, w2 = H^T w1, assemble
    const float pM0 = (float)(-dLRS * 20.0  * dpow(dC, 19));
    const float pM1 = (float)( dLRS * dLRS * 190.0  * dpow(dC, 18));
    const float pM2 = (float)(-dLRS * dLRS * dLRS * 1140.0 * dpow(dC, 17));
    const float pY0 = (float)( dLRS * dD0());
    const float pY1 = (float)(-dLRS * dLRS * dD1());
    const float pY2 = (float)( dLRS * dLRS * dLRS * dD2());
    const float kG0 = (float)dpow(dC, 20);

    const int row0 = wid * 16 + lg * 4;

    // fill A: Ss[col][k] = bf16(q[k] + 1) for all 16 cols (column-broadcast)
    {
        const int ct = t & 15, k0 = (t >> 4) * 4;
        short4 sp;
        sp.x = f2bf(Ms[(k0 + 0) * 16 + 8] + 1.0f);
        sp.y = f2bf(Ms[(k0 + 1) * 16 + 8] + 1.0f);
        sp.z = f2bf(Ms[(k0 + 2) * 16 + 8] + 1.0f);
        sp.w = f2bf(Ms[(k0 + 3) * 16 + 8] + 1.0f);
        *(short4*)(&Ss[ct * 72 + k0]) = sp;
    }
    // q at this thread's rows + full sum of q (butterfly; per-wave redundant)
    const float q0 = Ms[(row0 + 0) * 16 + 8];
    const float q1 = Ms[(row0 + 1) * 16 + 8];
    const float q2 = Ms[(row0 + 2) * 16 + 8];
    const float q3 = Ms[(row0 + 3) * 16 + 8];
    float qsum = Ms[lane * 16 + 8];
    #pragma unroll
    for (int m = 1; m < 64; m <<= 1) qsum += __shfl_xor(qsum, m, 64);
    const float w1b = qsum + 64.0f;          // 1^T q + 64

    const bf16x8 ga0 = *(const bf16x8*)(&Gs[(wid * 16 + lr) * 72 +  0 + lg * 8]);
    const bf16x8 ga1 = *(const bf16x8*)(&Gs[(wid * 16 + lr) * 72 + 32 + lg * 8]);

    __syncthreads();                         // fill-A visible
    // MFMA A: w1_X = G (q + 1); rows row0..row0+3 at this lane (repl over lr)
    float w10, w11, w12, w13;
    {
        const bf16x8 sb0 = *(const bf16x8*)(&Ss[lr * 72 +  0 + lg * 8]);
        const bf16x8 sb1 = *(const bf16x8*)(&Ss[lr * 72 + 32 + lg * 8]);
        f32x4 o = {0.f, 0.f, 0.f, 0.f};
        o = MFMA16(ga0, sb0, o);
        o = MFMA16(ga1, sb1, o);
        w10 = o[0]; w11 = o[1]; w12 = o[2]; w13 = o[3];
    }
    // wave row-sum of w1: values are lr-replicated, so reduce over lg only
    float val = (w10 + w11) + (w12 + w13);
    val += __shfl_xor(val, 16, 64);
    val += __shfl_xor(val, 32, 64);
    if (lane == 0) red[wid] = val;
    __syncthreads();                         // Ss reads done; red visible

    // fill B: t1 = w1 + w1b at own rows, col = lr (covers all 16 cols)
    {
        short4 sp;
        sp.x = f2bf(w10 + w1b); sp.y = f2bf(w11 + w1b);
        sp.z = f2bf(w12 + w1b); sp.w = f2bf(w13 + w1b);
        *(short4*)(&Ss[lr * 72 + row0]) = sp;
    }
    const float w1sum = red[0] + red[1] + red[2] + red[3];
    const float w2b = w1sum + 64.0f * w1b;   // 1^T w1_X + 64 w1b
    __syncthreads();                         // fill-B visible

    // MFMA B: w2_X = G (w1_X + w1b)
    float w20, w21, w22, w23;
    {
        const bf16x8 sb0 = *(const bf16x8*)(&Ss[lr * 72 +  0 + lg * 8]);
        const bf16x8 sb1 = *(const bf16x8*)(&Ss[lr * 72 + 32 + lg * 8]);
        f32x4 o = {0.f, 0.f, 0.f, 0.f};
        o = MFMA16(ga0, sb0, o);
        o = MFMA16(ga1, sb1, o);
        w20 = o[0]; w21 = o[1]; w22 = o[2]; w23 = o[3];
    }

    // assemble: a_k = uM(k)+cM multiplies M0 rows; y_k = uY(k)+cY -> label col
    const float cM  = pM0 + pM1 * w1b + pM2 * w2b;
    const float cY  = pY0 + pY1 * w1b + pY2 * w2b;
    const float sb0c = kG0 + pM0 * w1b + pM1 * w2b;   // F^20 z0 b-coefficient

    // all values lr-replicated -> compute on all lanes, reduce over lg only
    float acc[8] = {0.f, 0.f, 0.f, 0.f, 0.f, 0.f, 0.f, 0.f};
    {
        const float qs[4]  = {q0, q1, q2, q3};
        const float w1s[4] = {w10, w11, w12, w13};
        const float w2s[4] = {w20, w21, w22, w23};
        #pragma unroll
        for (int r = 0; r < 4; ++r) {
            const int row = row0 + r;
            const float a = pM0 * qs[r] + pM1 * w1s[r] + pM2 * w2s[r] + cM;
            const float y = pY0 * qs[r] + pY1 * w1s[r] + pY2 * w2s[r] + cY;
            const int lab = lab_s[row];
            const float4 mlo = *(const float4*)(&Ms[row * 16 + 0]);
            const float4 mhi = *(const float4*)(&Ms[row * 16 + 4]);
            acc[0] += a * mlo.x + ((lab == 0) ? y : 0.f);
            acc[1] += a * mlo.y + ((lab == 1) ? y : 0.f);
            acc[2] += a * mlo.z + ((lab == 2) ? y : 0.f);
            acc[3] += a * mlo.w + ((lab == 3) ? y : 0.f);
            acc[4] += a * mhi.x + ((lab == 4) ? y : 0.f);
            acc[5] += a * mhi.y + ((lab == 5) ? y : 0.f);
            acc[6] += a * mhi.z + ((lab == 6) ? y : 0.f);
            acc[7] += a * mhi.w + ((lab == 7) ? y : 0.f);
        }
    }
    #pragma unroll
    for (int j = 0; j < 8; ++j) {
        acc[j] += __shfl_xor(acc[j], 16, 64);
        acc[j] += __shfl_xor(acc[j], 32, 64);
    }
    if (lane == 0) {
        #pragma unroll
        for (int j = 0; j < 8; ++j) red[16 + wid * 8 + j] = acc[j];
    }
    __syncthreads();
    if (t < 8) {
        const float s = red[16 + 0 * 8 + t] + red[16 + 1 * 8 + t] +
                        red[16 + 2 * 8 + t] + red[16 + 3 * 8 + t];
        // thread t: lr == t -> bc = b0[t]
        out[b * LL + t] = kG0 * p0_s[t] + sb0c * bc + s;
    }
}

extern "C" void kernel_launch(void* const* d_in, const int* in_sizes, int n_in,
                              void* d_out, int out_size, void* d_ws, size_t ws_size,
                              hipStream_t stream) {
    const float* demo   = (const float*)d_in[0]; // demo_embeddings [512,64,1024]
    const float* emb    = (const float*)d_in[1]; // embeddings     [512,1024]
    const float* W0     = (const float*)d_in[2]; // W0             [512,8,1024]
    const float* b0     = (const float*)d_in[3]; // b0             [512,8]
    const int*   labels = (const int*)d_in[4];   // demo_labels    [512,64]
    float* out = (float*)d_out;                  // logits         [512,8] f32
    (void)in_sizes; (void)n_in; (void)out_size; (void)d_ws; (void)ws_size;
    hipLaunchKernelGGL(knn_linear_fix_kernel, dim3(BB), dim3(256), 0, stream,
                       demo, emb, W0, b0, labels, out);
}

// Round 9
// 29.434 us; speedup vs baseline: 1.4933x; 1.0014x over previous
//
#include <hip/hip_runtime.h>

// KnnLinearFixModel: B=512, K=64, D=1024, L=8, 20 SGD steps.
// W_t = c^t*W0 + S_t^T X (c=1-LR*WD) -> phase 1 computes G=X*X^T, M0=X*W0^T,
// q=X*e, p0=W0*e in one pass (MFMA Gram trick, R5). Phase 3 closed form (R6):
// logits = c^20 p0 + w^T z_20 via binomial expansion in H (2 G-matvecs).
// Phase 2 vectorized reduce (R8).
// R9: (1) prologue reorder -- small label/bias loads issue BEFORE chunk-0's 19
// loads, their LDS writes after (no standalone ~900cy bubble); (2) phase-1
// split-half store/load interleave: store X rows 0..31, reissue those 8 regs
// for ch+1, store rows 32..63+P, reissue the other 11 -> memory pipe refills
// half a store earlier per chunk with no extra live VGPRs (R7's depth-2
// lesson: live-buffer growth spills).

#define BB 512
#define KK 64
#define DD 1024
#define LL 8

#define SROWS 80             // 64 X rows + 16 P rows (0-7 W0, 8 e, 9-15 zero)
#define SSTR  72             // shorts/row: 144 B, 16B-aligned rows for b128
#define NTILE 15             // 10 G (upper tri) + 4 M + 1 PP
#define ARENA_BYTES (4 * NTILE * 256 * 4)   // 61440; staging needs 4*11520

typedef __attribute__((ext_vector_type(8))) short bf16x8;
typedef __attribute__((ext_vector_type(4))) float f32x4;

// ---- compile-time coefficient algebra (double, exact enough) ----
constexpr double dLRS = 1e-4 * 2.0 / (64.0 * 8.0);   // LR*scale = 3.90625e-7
constexpr double dC   = 1.0 - 1e-4 * 0.01;           // c = 1 - LR*WD
constexpr double dpow(double x, int n) { double r = 1; for (int i = 0; i < n; ++i) r *= x; return r; }
// P1 = sum_{t=0..19} c^t F^{19-t} = sum_m C(20,m+1) c^{19-m} (-LRS H)^m
// P2 = sum_{j=0..19} F^j        = sum_m D_m (-LRS H)^m, D_m = sum_j C(j,m)c^{j-m}
// F^20 = sum_m C(20,m) c^{20-m} (-LRS H)^m
constexpr double dD0() { double s = 0; for (int j = 0; j < 20; ++j) s += dpow(dC, j); return s; }
constexpr double dD1() { double s = 0; for (int j = 1; j < 20; ++j) s += j * dpow(dC, j - 1); return s; }
constexpr double dD2() { double s = 0; for (int j = 2; j < 20; ++j) s += (j * (j - 1) / 2) * dpow(dC, j - 2); return s; }

__device__ __forceinline__ short f2bf(float f) {
    // round-to-nearest-even f32 -> bf16 (finite inputs only)
    unsigned u = __float_as_uint(f);
    unsigned r = (u + 0x7FFFu + ((u >> 16) & 1u)) >> 16;
    return (short)r;
}

#define MFMA16(A, B, C) __builtin_amdgcn_mfma_f32_16x16x32_bf16(A, B, C, 0, 0, 0)

__global__ __launch_bounds__(256, 2)
void knn_linear_fix_kernel(const float* __restrict__ demo,   // [B,K,D]
                           const float* __restrict__ emb,    // [B,D]
                           const float* __restrict__ W0,     // [B,L,D]
                           const float* __restrict__ b0,     // [B,L]
                           const int*   __restrict__ labels, // [B,K]
                           float* __restrict__ out)          // [B,L]
{
    const int b    = blockIdx.x;
    const int t    = threadIdx.x;
    const int lane = t & 63;
    const int wid  = t >> 6;          // wave id 0..3 == D-slice id
    const int lg   = lane >> 4;       // lane group 0..3
    const int lr   = lane & 15;       // row (A) / col (B, C/D) index

    __shared__ __align__(16) char arena[ARENA_BYTES]; // staging / exchange
    __shared__ short Gs[64 * 72];    // G bf16, stride 72
    __shared__ short Ss[16 * 72];    // broadcast t-vector as B-frag [col][k]
    __shared__ float Ms[64 * 16];    // cols 0-7 = M0 = X W0^T, col 8 = q = X.e
    __shared__ float red[256];
    __shared__ float p0_s[16];       // p0 = W0 . e
    __shared__ int   lab_s[64];

    const float* Xg = demo + (size_t)b * (KK * DD);
    const float* Wg = W0   + (size_t)b * (LL * DD);
    const float* eg = emb  + (size_t)b * DD;

    short* Xw = (short*)arena + wid * (SROWS * SSTR);  // wave-private staging
    float* Ex = (float*)arena;                         // exchange view

    const int g  = lane >> 4;        // load row-group 0..3
    const int cl = (lane & 15) * 4;  // load col (floats): 16 lanes x 16B = 256B

    float4 xb[16]; float4 pb[3];

#define LOADLO(CH) do {                                                          \
        const int doff = wid * 256 + (CH) * 64;                                  \
        _Pragma("unroll")                                                        \
        for (int r = 0; r < 8; ++r)                                              \
            xb[r] = *(const float4*)(Xg + (size_t)(r * 4 + g) * DD + doff + cl); \
    } while (0)

#define LOADHI(CH) do {                                                          \
        const int doff = wid * 256 + (CH) * 64;                                  \
        _Pragma("unroll")                                                        \
        for (int r = 8; r < 16; ++r)                                             \
            xb[r] = *(const float4*)(Xg + (size_t)(r * 4 + g) * DD + doff + cl); \
        pb[0] = *(const float4*)(Wg + (size_t)(g    ) * DD + doff + cl);         \
        pb[1] = *(const float4*)(Wg + (size_t)(g + 4) * DD + doff + cl);         \
        pb[2] = (g == 0) ? *(const float4*)(eg + doff + cl)                      \
                         : make_float4(0.f, 0.f, 0.f, 0.f);                      \
    } while (0)

#define ST1(ROW, V) do {                                                         \
        short4 h;                                                                \
        h.x = f2bf((V).x); h.y = f2bf((V).y);                                    \
        h.z = f2bf((V).z); h.w = f2bf((V).w);                                    \
        *(short4*)(&Xw[(ROW) * SSTR + cl]) = h;                                  \
    } while (0)

#define STORELO() do {                                                           \
        _Pragma("unroll")                                                        \
        for (int r = 0; r < 8; ++r) ST1(r * 4 + g, xb[r]);                       \
    } while (0)

#define STOREHI() do {                                                           \
        _Pragma("unroll")                                                        \
        for (int r = 8; r < 16; ++r) ST1(r * 4 + g, xb[r]);                      \
        ST1(64 + g, pb[0]);                                                      \
        ST1(68 + g, pb[1]);                                                      \
        if (g == 0) ST1(72, pb[2]);                                              \
    } while (0)

#define FRAG(I, KS) (*(const bf16x8*)(&Xw[(16 * (I) + lr) * SSTR + lg * 8 + (KS) * 32]))
#define FRAGP(KS)   (*(const bf16x8*)(&Xw[(64 + lr) * SSTR + lg * 8 + (KS) * 32]))

    f32x4 g00 = {0,0,0,0}, g01 = {0,0,0,0}, g02 = {0,0,0,0}, g03 = {0,0,0,0};
    f32x4 g11 = {0,0,0,0}, g12 = {0,0,0,0}, g13 = {0,0,0,0};
    f32x4 g22 = {0,0,0,0}, g23 = {0,0,0,0}, g33 = {0,0,0,0};
    f32x4 am0 = {0,0,0,0}, am1 = {0,0,0,0}, am2 = {0,0,0,0}, am3 = {0,0,0,0};
    f32x4 app = {0,0,0,0};

    // ---------------- Phase 1 prologue: small loads FIRST (retire first),
    // then chunk-0's 19 big loads; LDS writes / init after (no drain: in-order
    // vmcnt retirement means waiting on the small loads leaves 19 in flight).
    int labv = 0;
    if (t < 64) labv = labels[b * KK + t];
    float bc = (lr < 8) ? b0[b * LL + lr] : 0.0f;      // bias, replicated
    LOADLO(0); LOADHI(0);
    if (t < 64) lab_s[t] = labv;
    {   // zero wave-private staging pad rows 73..79 (P rows 9-15), once
        int* zp = (int*)(Xw + 73 * SSTR);
        for (int i = lane; i < (7 * SSTR) / 2; i += 64) zp[i] = 0;
    }

    // ---------------- Phase 1: 4 chunks of 64 cols per wave, no barriers;
    // split-half store/load interleave refills the memory pipe mid-store.
    for (int ch = 0; ch < 4; ++ch) {
        STORELO();                       // waits xb[0..7] of chunk ch
        if (ch < 3) LOADLO(ch + 1);      // reissue those 8 regs for ch+1
        STOREHI();                       // waits xb[8..15], pb of chunk ch
        if (ch < 3) LOADHI(ch + 1);      // reissue the other 11
        __builtin_amdgcn_sched_barrier(0);
        #pragma unroll
        for (int ks = 0; ks < 2; ++ks) {
            const bf16x8 f0 = FRAG(0, ks), f1 = FRAG(1, ks);
            const bf16x8 f2 = FRAG(2, ks), f3 = FRAG(3, ks);
            const bf16x8 fp = FRAGP(ks);
            g00 = MFMA16(f0, f0, g00); g01 = MFMA16(f0, f1, g01);
            g02 = MFMA16(f0, f2, g02); g03 = MFMA16(f0, f3, g03);
            g11 = MFMA16(f1, f1, g11); g12 = MFMA16(f1, f2, g12);
            g13 = MFMA16(f1, f3, g13);
            g22 = MFMA16(f2, f2, g22); g23 = MFMA16(f2, f3, g23);
            g33 = MFMA16(f3, f3, g33);
            am0 = MFMA16(f0, fp, am0); am1 = MFMA16(f1, fp, am1);
            am2 = MFMA16(f2, fp, am2); am3 = MFMA16(f3, fp, am3);
            app = MFMA16(fp, fp, app);
        }
        __builtin_amdgcn_sched_barrier(0);
    }

    // ---------------- Phase 2: cross-wave f32 reduce of 15 tiles (vectorized)
    __syncthreads();                    // staging regions -> exchange arena
    {
        float* Exw = Ex + wid * (NTILE * 256);
        const int ro = (lg * 4) * 16 + lr;   // C/D: row=lg*4+r, col=lr
#define PUT(IDX, ACC) { _Pragma("unroll") \
        for (int r = 0; r < 4; ++r) Exw[(IDX) * 256 + ro + r * 16] = (ACC)[r]; }
        PUT(0, g00) PUT(1, g01) PUT(2, g02) PUT(3, g03)
        PUT(4, g11) PUT(5, g12) PUT(6, g13)
        PUT(7, g22) PUT(8, g23) PUT(9, g33)
        PUT(10, am0) PUT(11, am1) PUT(12, am2) PUT(13, am3)
        PUT(14, app)
#undef PUT
    }
    __syncthreads();
    {
        const float4* E0 = (const float4*)(Ex + 0 * NTILE * 256);
        const float4* E1 = (const float4*)(Ex + 1 * NTILE * 256);
        const float4* E2 = (const float4*)(Ex + 2 * NTILE * 256);
        const float4* E3 = (const float4*)(Ex + 3 * NTILE * 256);
        // G tiles: 10*256 f32 = 640 float4s
        #pragma unroll
        for (int p = 0; p < 3; ++p) {
            const int fid = p * 256 + t;
            if (fid < 640) {
                float4 v = E0[fid];
                v.x += E1[fid].x; v.y += E1[fid].y; v.z += E1[fid].z; v.w += E1[fid].w;
                v.x += E2[fid].x; v.y += E2[fid].y; v.z += E2[fid].z; v.w += E2[fid].w;
                v.x += E3[fid].x; v.y += E3[fid].y; v.z += E3[fid].z; v.w += E3[fid].w;
                const int idx = fid * 4;
                const int s   = idx >> 8;          // tile 0..9 (upper triangle)
                const int rem = idx & 255;
                const int er  = rem >> 4, ec = rem & 15;   // ec in {0,4,8,12}
                const int ti  = (s >= 4) + (s >= 7) + (s >= 9);
                const int st  = (ti == 0) ? 0 : (ti == 1) ? 4 : (ti == 2) ? 7 : 9;
                const int tj  = ti + (s - st);
                const int gr  = ti * 16 + er, gc = tj * 16 + ec;
                short4 gv;
                gv.x = f2bf(v.x); gv.y = f2bf(v.y);
                gv.z = f2bf(v.z); gv.w = f2bf(v.w);
                *(short4*)(&Gs[gr * 72 + gc]) = gv;        // primary (upper)
                Gs[(gc + 0) * 72 + gr] = gv.x;             // mirror (lower)
                Gs[(gc + 1) * 72 + gr] = gv.y;
                Gs[(gc + 2) * 72 + gr] = gv.z;
                Gs[(gc + 3) * 72 + gr] = gv.w;
            }
        }
        // M tiles + PP: 5*256 f32 = 320 float4s (offset 640)
        #pragma unroll
        for (int p = 0; p < 2; ++p) {
            const int fid = p * 256 + t;
            if (fid < 320) {
                const int f = 640 + fid;
                float4 v = E0[f];
                v.x += E1[f].x; v.y += E1[f].y; v.z += E1[f].z; v.w += E1[f].w;
                v.x += E2[f].x; v.y += E2[f].y; v.z += E2[f].z; v.w += E2[f].w;
                v.x += E3[f].x; v.y += E3[f].y; v.z += E3[f].z; v.w += E3[f].w;
                const int idx = fid * 4;
                const int mt  = idx >> 8;          // 0..3 = M tiles, 4 = PP
                const int rem = idx & 255;
                const int er  = rem >> 4, ec = rem & 15;
                if (mt < 4) {
                    *(float4*)(&Ms[(mt * 16 + er) * 16 + ec]) = v;
                } else if (er == 8) {              // row 8 of P P^T = e.P[col]
                    p0_s[ec + 0] = v.x; p0_s[ec + 1] = v.y;
                    p0_s[ec + 2] = v.z; p0_s[ec + 3] = v.w;
                }
            }
        }
    }
    __syncthreads();

    // ---------------- Phase 3 (closed form): w1 = H^T w, w2 = H^T w1, assemble
    const float pM0 = (float)(-dLRS * 20.0  * dpow(dC, 19));
    const float pM1 = (float)( dLRS * dLRS * 190.0  * dpow(dC, 18));
    const float pM2 = (float)(-dLRS * dLRS * dLRS * 1140.0 * dpow(dC, 17));
    const float pY0 = (float)( dLRS * dD0());
    const float pY1 = (float)(-dLRS * dLRS * dD1());
    const float pY2 = (float)( dLRS * dLRS * dLRS * dD2());
    const float kG0 = (float)dpow(dC, 20);

    const int row0 = wid * 16 + lg * 4;

    // fill A: Ss[col][k] = bf16(q[k] + 1) for all 16 cols (column-broadcast)
    {
        const int ct = t & 15, k0 = (t >> 4) * 4;
        short4 sp;
        sp.x = f2bf(Ms[(k0 + 0) * 16 + 8] + 1.0f);
        sp.y = f2bf(Ms[(k0 + 1) * 16 + 8] + 1.0f);
        sp.z = f2bf(Ms[(k0 + 2) * 16 + 8] + 1.0f);
        sp.w = f2bf(Ms[(k0 + 3) * 16 + 8] + 1.0f);
        *(short4*)(&Ss[ct * 72 + k0]) = sp;
    }
    // q at this thread's rows + full sum of q (butterfly; per-wave redundant)
    const float q0 = Ms[(row0 + 0) * 16 + 8];
    const float q1 = Ms[(row0 + 1) * 16 + 8];
    const float q2 = Ms[(row0 + 2) * 16 + 8];
    const float q3 = Ms[(row0 + 3) * 16 + 8];
    float qsum = Ms[lane * 16 + 8];
    #pragma unroll
    for (int m = 1; m < 64; m <<= 1) qsum += __shfl_xor(qsum, m, 64);
    const float w1b = qsum + 64.0f;          // 1^T q + 64

    const bf16x8 ga0 = *(const bf16x8*)(&Gs[(wid * 16 + lr) * 72 +  0 + lg * 8]);
    const bf16x8 ga1 = *(const bf16x8*)(&Gs[(wid * 16 + lr) * 72 + 32 + lg * 8]);

    __syncthreads();                         // fill-A visible
    // MFMA A: w1_X = G (q + 1); rows row0..row0+3 at this lane (repl over lr)
    float w10, w11, w12, w13;
    {
        const bf16x8 sb0 = *(const bf16x8*)(&Ss[lr * 72 +  0 + lg * 8]);
        const bf16x8 sb1 = *(const bf16x8*)(&Ss[lr * 72 + 32 + lg * 8]);
        f32x4 o = {0.f, 0.f, 0.f, 0.f};
        o = MFMA16(ga0, sb0, o);
        o = MFMA16(ga1, sb1, o);
        w10 = o[0]; w11 = o[1]; w12 = o[2]; w13 = o[3];
    }
    // wave row-sum of w1: values are lr-replicated, so reduce over lg only
    float val = (w10 + w11) + (w12 + w13);
    val += __shfl_xor(val, 16, 64);
    val += __shfl_xor(val, 32, 64);
    if (lane == 0) red[wid] = val;
    __syncthreads();                         // Ss reads done; red visible

    // fill B: t1 = w1 + w1b at own rows, col = lr (covers all 16 cols)
    {
        short4 sp;
        sp.x = f2bf(w10 + w1b); sp.y = f2bf(w11 + w1b);
        sp.z = f2bf(w12 + w1b); sp.w = f2bf(w13 + w1b);
        *(short4*)(&Ss[lr * 72 + row0]) = sp;
    }
    const float w1sum = red[0] + red[1] + red[2] + red[3];
    const float w2b = w1sum + 64.0f * w1b;   // 1^T w1_X + 64 w1b
    __syncthreads();                         // fill-B visible

    // MFMA B: w2_X = G (w1_X + w1b)
    float w20, w21, w22, w23;
    {
        const bf16x8 sb0 = *(const bf16x8*)(&Ss[lr * 72 +  0 + lg * 8]);
        const bf16x8 sb1 = *(const bf16x8*)(&Ss[lr * 72 + 32 + lg * 8]);
        f32x4 o = {0.f, 0.f, 0.f, 0.f};
        o = MFMA16(ga0, sb0, o);
        o = MFMA16(ga1, sb1, o);
        w20 = o[0]; w21 = o[1]; w22 = o[2]; w23 = o[3];
    }

    // assemble: a_k = uM(k)+cM multiplies M0 rows; y_k = uY(k)+cY -> label col
    const float cM  = pM0 + pM1 * w1b + pM2 * w2b;
    const float cY  = pY0 + pY1 * w1b + pY2 * w2b;
    const float sb0c = kG0 + pM0 * w1b + pM1 * w2b;   // F^20 z0 b-coefficient

    // all values lr-replicated -> compute on all lanes, reduce over lg only
    float acc[8] = {0.f, 0.f, 0.f, 0.f, 0.f, 0.f, 0.f, 0.f};
    {
        const float qs[4]  = {q0, q1, q2, q3};
        const float w1s[4] = {w10, w11, w12, w13};
        const float w2s[4] = {w20, w21, w22, w23};
        #pragma unroll
        for (int r = 0; r < 4; ++r) {
            const int row = row0 + r;
            const float a = pM0 * qs[r] + pM1 * w1s[r] + pM2 * w2s[r] + cM;
            const float y = pY0 * qs[r] + pY1 * w1s[r] + pY2 * w2s[r] + cY;
            const int lab = lab_s[row];
            const float4 mlo = *(const float4*)(&Ms[row * 16 + 0]);
            const float4 mhi = *(const float4*)(&Ms[row * 16 + 4]);
            acc[0] += a * mlo.x + ((lab == 0) ? y : 0.f);
            acc[1] += a * mlo.y + ((lab == 1) ? y : 0.f);
            acc[2] += a * mlo.z + ((lab == 2) ? y : 0.f);
            acc[3] += a * mlo.w + ((lab == 3) ? y : 0.f);
            acc[4] += a * mhi.x + ((lab == 4) ? y : 0.f);
            acc[5] += a * mhi.y + ((lab == 5) ? y : 0.f);
            acc[6] += a * mhi.z + ((lab == 6) ? y : 0.f);
            acc[7] += a * mhi.w + ((lab == 7) ? y : 0.f);
        }
    }
    #pragma unroll
    for (int j = 0; j < 8; ++j) {
        acc[j] += __shfl_xor(acc[j], 16, 64);
        acc[j] += __shfl_xor(acc[j], 32, 64);
    }
    if (lane == 0) {
        #pragma unroll
        for (int j = 0; j < 8; ++j) red[16 + wid * 8 + j] = acc[j];
    }
    __syncthreads();
    if (t < 8) {
        const float s = red[16 + 0 * 8 + t] + red[16 + 1 * 8 + t] +
                        red[16 + 2 * 8 + t] + red[16 + 3 * 8 + t];
        // thread t: lr == t -> bc = b0[t]
        out[b * LL + t] = kG0 * p0_s[t] + sb0c * bc + s;
    }
}

extern "C" void kernel_launch(void* const* d_in, const int* in_sizes, int n_in,
                              void* d_out, int out_size, void* d_ws, size_t ws_size,
                              hipStream_t stream) {
    const float* demo   = (const float*)d_in[0]; // demo_embeddings [512,64,1024]
    const float* emb    = (const float*)d_in[1]; // embeddings     [512,1024]
    const float* W0     = (const float*)d_in[2]; // W0             [512,8,1024]
    const float* b0     = (const float*)d_in[3]; // b0             [512,8]
    const int*   labels = (const int*)d_in[4];   // demo_labels    [512,64]
    float* out = (float*)d_out;                  // logits         [512,8] f32
    (void)in_sizes; (void)n_in; (void)out_size; (void)d_ws; (void)ws_size;
    hipLaunchKernelGGL(knn_linear_fix_kernel, dim3(BB), dim3(256), 0, stream,
                       demo, emb, W0, b0, labels, out);
}